// Round 9
// baseline (225.272 us; speedup 1.0000x reference)
//
#include <hip/hip_runtime.h>
#include <stdint.h>

#define BATCH 16
#define DQ 768
#define NQ 1024      // T*Hp*Wp
#define NT 64
#define DKV 384
#define NHEAD 12
#define HD 64
#define HD2 32

typedef __attribute__((ext_vector_type(8))) short bf16x8;
typedef __attribute__((ext_vector_type(4))) float f32x4;

__device__ __forceinline__ unsigned short f2bf(float f) {
    unsigned u = __float_as_uint(f);
    u += 0x7fff + ((u >> 16) & 1);          // RNE (inputs finite)
    return (unsigned short)(u >> 16);
}
__device__ __forceinline__ float bf2f(unsigned short h) {
    return __uint_as_float((unsigned)h << 16);
}

__device__ __forceinline__ void gload_lds16(const void* g, void* l) {
    __builtin_amdgcn_global_load_lds(
        (const __attribute__((address_space(1))) unsigned int*)g,
        (__attribute__((address_space(3))) unsigned int*)l, 16, 0, 0);
}

// ---------------------------------------------------------------------------
// RoPE table: tab[p][0..31]=cos(p*inv(d)), tab[p][32..63]=sin(p*inv(d))
// (fills the featT region AFTER gemm_q is done with it)
// ---------------------------------------------------------------------------
__global__ void rope_tab_k(float* __restrict__ tab) {
    const int p = blockIdx.x;
    const int d = threadIdx.x;   // 0..31
    float inv = exp2f((float)d * -0.41524101186092029f);  // -log2(1e4)/32
    float s, c; __sincosf((float)p * inv, &s, &c);
    tab[p * 64 + d] = c;
    tab[p * 64 + 32 + d] = s;
}

// ---------------------------------------------------------------------------
// Transpose + f32->bf16: featT[b][n][c] = feat[b][c][n]
// ---------------------------------------------------------------------------
__global__ __launch_bounds__(256) void conv_feat_k(const float* __restrict__ feat,
                                                   unsigned short* __restrict__ featT) {
    const int b = blockIdx.z;
    const int n0 = blockIdx.x * 64;
    const int c0 = blockIdx.y * 64;
    __shared__ float T[64][65];
    const int tid = threadIdx.x;
    const int r = tid >> 4, c4 = (tid & 15) * 4;
    const float* fb = feat + (size_t)b * DQ * NQ + (size_t)c0 * NQ + n0;
    for (int rr = 0; rr < 64; rr += 16) {
        float4 v = *(const float4*)(fb + (size_t)(rr + r) * NQ + c4);
        T[rr + r][c4 + 0] = v.x; T[rr + r][c4 + 1] = v.y;
        T[rr + r][c4 + 2] = v.z; T[rr + r][c4 + 3] = v.w;
    }
    __syncthreads();
    unsigned short* ob = featT + ((size_t)b * NQ + n0) * DQ + c0;
    for (int rr = 0; rr < 64; rr += 16) {
        int dr = rr + r;   // local n
        ushort4 w;
        w.x = f2bf(T[c4 + 0][dr]); w.y = f2bf(T[c4 + 1][dr]);
        w.z = f2bf(T[c4 + 2][dr]); w.w = f2bf(T[c4 + 3][dr]);
        *(ushort4*)(ob + (size_t)dr * DQ + c4) = w;
    }
}

// ---------------------------------------------------------------------------
// Transpose + f32->bf16 for both weights: WqT[j][c]=Wq[c][j], WoutT[d][j]=Wout[j][d]
// ---------------------------------------------------------------------------
__global__ __launch_bounds__(256) void conv_w_k(const float* __restrict__ Wq,
                                                const float* __restrict__ Wout,
                                                unsigned short* __restrict__ WqT,
                                                unsigned short* __restrict__ WoutT) {
    const float* src = blockIdx.z ? Wout : Wq;
    unsigned short* dst = blockIdx.z ? WoutT : WqT;
    const int r0 = blockIdx.x * 64;   // src row tile
    const int c0 = blockIdx.y * 64;   // src col tile
    __shared__ float T[64][65];
    const int tid = threadIdx.x;
    const int r = tid >> 4, c4 = (tid & 15) * 4;
    for (int rr = 0; rr < 64; rr += 16) {
        float4 v = *(const float4*)(src + (size_t)(r0 + rr + r) * DQ + c0 + c4);
        T[rr + r][c4 + 0] = v.x; T[rr + r][c4 + 1] = v.y;
        T[rr + r][c4 + 2] = v.z; T[rr + r][c4 + 3] = v.w;
    }
    __syncthreads();
    for (int rr = 0; rr < 64; rr += 16) {
        int dr = rr + r;
        ushort4 w;
        w.x = f2bf(T[c4 + 0][dr]); w.y = f2bf(T[c4 + 1][dr]);
        w.z = f2bf(T[c4 + 2][dr]); w.w = f2bf(T[c4 + 3][dr]);
        *(ushort4*)(dst + (size_t)(c0 + dr) * DQ + r0 + c4) = w;
    }
}

// ---------------------------------------------------------------------------
// kv = tokens @ Wkv  (f32, small: 1.2 GF)
// ---------------------------------------------------------------------------
__global__ __launch_bounds__(256) void gemm_kv_k(const float* __restrict__ tokens,
                                                 const float* __restrict__ Wkv,
                                                 float* __restrict__ kv_out) {
    const int b = blockIdx.z;
    const int j0 = blockIdx.x * 64;
    __shared__ float As[16][64];
    __shared__ float Bs[16][64];
    const int tid = threadIdx.x;
    const int tx = tid & 15, ty = tid >> 4;
    float acc[4][4] = {};
    const float* tb = tokens + (size_t)b * NT * DKV;
    for (int c0 = 0; c0 < DKV; c0 += 16) {
        {
            int m = tid >> 2, jq = tid & 3;
            float4 v = *(const float4*)(tb + (size_t)m * DKV + c0 + jq * 4);
            As[jq * 4 + 0][m] = v.x; As[jq * 4 + 1][m] = v.y;
            As[jq * 4 + 2][m] = v.z; As[jq * 4 + 3][m] = v.w;
            int kk = tid >> 4, n4 = (tid & 15) * 4;
            *(float4*)&Bs[kk][n4] = *(const float4*)(Wkv + (size_t)(c0 + kk) * (2 * DQ) + j0 + n4);
        }
        __syncthreads();
#pragma unroll
        for (int kk = 0; kk < 16; ++kk) {
            float a[4], bb[4];
            *(float4*)a  = *(float4*)&As[kk][ty * 4];
            *(float4*)bb = *(float4*)&Bs[kk][tx * 4];
#pragma unroll
            for (int i = 0; i < 4; ++i)
#pragma unroll
                for (int j = 0; j < 4; ++j)
                    acc[i][j] += a[i] * bb[j];
        }
        __syncthreads();
    }
    float* ob = kv_out + (size_t)b * NT * (2 * DQ);
#pragma unroll
    for (int i = 0; i < 4; ++i)
        *(float4*)(ob + (size_t)(ty * 4 + i) * (2 * DQ) + j0 + tx * 4) = *(float4*)acc[i];
}

// ---------------------------------------------------------------------------
// MFMA GEMM, counted-vmcnt pipeline (3 bufs, depth 2), LDS-bounced coalesced
// bf16 C-write. q[b][n][j] = featT[b][n][:] . WqT[j][:]
// ---------------------------------------------------------------------------
__global__ __launch_bounds__(256) void gemm_q_mfma(const unsigned short* __restrict__ At,
                                                   const unsigned short* __restrict__ Bt,
                                                   unsigned short* __restrict__ C) {
    const int b = blockIdx.z;
    const int m0 = blockIdx.x * 128;
    const int n0 = blockIdx.y * 128;
    __shared__ __align__(16) unsigned short ldsAll[6][128 * 32];  // A=0..2, B=3..5
    const int tid = threadIdx.x;
    const int lane = tid & 63;
    const int wm = ((tid >> 7) & 1) * 64;      // wave m offset
    const int wn = ((tid >> 6) & 1) * 64;      // wave n offset
    const int fr = lane & 15;
    const int fg = lane >> 4;
    const int pslot = (fg ^ ((fr >> 1) & 3)) * 16;   // physical 16B slot for frag reads
    const int wbase = (tid & 192) * 16;              // wave-uniform LDS byte base
    f32x4 acc[4][4] = {};

    const unsigned short* Ab = At + (size_t)b * NQ * DQ + (size_t)m0 * DQ;
    const unsigned short* Bb = Bt + (size_t)n0 * DQ;
    const int srow_lo = tid >> 2;
    const int sslot = tid & 3;

    auto STAGE = [&](int buf, int k0) {
#pragma unroll
        for (int i = 0; i < 2; ++i) {
            int row = i * 64 + srow_lo;
            int sl = sslot ^ ((row >> 1) & 3);
            gload_lds16(Ab + (size_t)row * DQ + k0 + sl * 8,
                        (char*)ldsAll[buf] + i * 4096 + wbase);
            gload_lds16(Bb + (size_t)row * DQ + k0 + sl * 8,
                        (char*)ldsAll[3 + buf] + i * 4096 + wbase);
        }
    };

    const int NSTEP = DQ / 32;   // 24
    STAGE(0, 0);
    STAGE(1, 32);                // 8 outstanding/thread
    int cur = 0;
    for (int t = 0; t < NSTEP; ++t) {
        if (t + 1 < NSTEP) {
            asm volatile("s_waitcnt vmcnt(4)" ::: "memory");   // tile t ready, t+1 in flight
        } else {
            asm volatile("s_waitcnt vmcnt(0)" ::: "memory");
        }
        __builtin_amdgcn_s_barrier();
        __builtin_amdgcn_sched_barrier(0);
        int nxt = cur + 2; if (nxt >= 3) nxt -= 3;
        if (t + 2 < NSTEP) STAGE(nxt, (t + 2) * 32);
        bf16x8 af[4], bfr[4];
#pragma unroll
        for (int f = 0; f < 4; ++f) {
            af[f]  = *(const bf16x8*)((const char*)ldsAll[cur]     + (wm + f * 16 + fr) * 64 + pslot);
            bfr[f] = *(const bf16x8*)((const char*)ldsAll[3 + cur] + (wn + f * 16 + fr) * 64 + pslot);
        }
#pragma unroll
        for (int i = 0; i < 4; ++i)
#pragma unroll
            for (int j = 0; j < 4; ++j)
                acc[i][j] = __builtin_amdgcn_mfma_f32_16x16x32_bf16(af[i], bfr[j], acc[i][j], 0, 0, 0);
        cur = cur + 1; if (cur >= 3) cur = 0;
    }
    // ---- LDS-bounce for coalesced bf16 writes ----
    __syncthreads();   // all frag reads done; safe to reuse staging LDS (32KB)
    unsigned short (*tile)[128] = (unsigned short (*)[128])&ldsAll[0][0];
#pragma unroll
    for (int i = 0; i < 4; ++i)
#pragma unroll
        for (int j = 0; j < 4; ++j)
#pragma unroll
            for (int r = 0; r < 4; ++r)
                tile[wm + i * 16 + fg * 4 + r][wn + j * 16 + fr] = f2bf(acc[i][j][r]);
    __syncthreads();
    unsigned short* Cb = C + (size_t)b * NQ * DQ;
#pragma unroll
    for (int v = 0; v < 8; ++v) {
        int flat8 = v * 256 + tid;       // 2048 x bf16x8 chunks
        int row = flat8 >> 4;
        int c8 = (flat8 & 15) * 8;
        bf16x8 val = *(const bf16x8*)&tile[row][c8];
        *(bf16x8*)(Cb + (size_t)(m0 + row) * DQ + n0 + c8) = val;
    }
}

// ---------------------------------------------------------------------------
// MFMA GEMM (transposed output, fused residual+bias), counted-vmcnt pipeline:
// out[b][d][n] = WoutT[d][:] . ao[b][n][:] + feat[b][d][n] + bout[d]
// ---------------------------------------------------------------------------
__global__ __launch_bounds__(256) void gemm_out_mfma(const unsigned short* __restrict__ At,
                                                     const unsigned short* __restrict__ Bt,
                                                     const float* __restrict__ feat,
                                                     const float* __restrict__ bout,
                                                     float* __restrict__ out) {
    const int b = blockIdx.z;
    const int m0 = blockIdx.x * 128;   // d
    const int n0 = blockIdx.y * 128;   // n
    __shared__ __align__(16) unsigned short ldsA[3][128 * 32];
    __shared__ __align__(16) unsigned short ldsB[3][128 * 32];
    const int tid = threadIdx.x;
    const int lane = tid & 63;
    const int wm = ((tid >> 7) & 1) * 64;
    const int wn = ((tid >> 6) & 1) * 64;
    const int fr = lane & 15;
    const int fg = lane >> 4;
    const int pslot = (fg ^ ((fr >> 1) & 3)) * 16;
    const int wbase = (tid & 192) * 16;
    f32x4 acc[4][4] = {};

    const unsigned short* Ab = At + (size_t)m0 * DQ;                          // WoutT (shared across b)
    const unsigned short* Bb = Bt + (size_t)b * NQ * DQ + (size_t)n0 * DQ;    // ao
    const int srow_lo = tid >> 2;
    const int sslot = tid & 3;

    auto STAGE = [&](int buf, int k0) {
#pragma unroll
        for (int i = 0; i < 2; ++i) {
            int row = i * 64 + srow_lo;
            int sl = sslot ^ ((row >> 1) & 3);
            gload_lds16(Ab + (size_t)row * DQ + k0 + sl * 8,
                        (char*)ldsA[buf] + i * 4096 + wbase);
            gload_lds16(Bb + (size_t)row * DQ + k0 + sl * 8,
                        (char*)ldsB[buf] + i * 4096 + wbase);
        }
    };

    const int NSTEP = DQ / 32;   // 24
    STAGE(0, 0);
    STAGE(1, 32);
    int cur = 0;
    for (int t = 0; t < NSTEP; ++t) {
        if (t + 1 < NSTEP) {
            asm volatile("s_waitcnt vmcnt(4)" ::: "memory");
        } else {
            asm volatile("s_waitcnt vmcnt(0)" ::: "memory");
        }
        __builtin_amdgcn_s_barrier();
        __builtin_amdgcn_sched_barrier(0);
        int nxt = cur + 2; if (nxt >= 3) nxt -= 3;
        if (t + 2 < NSTEP) STAGE(nxt, (t + 2) * 32);
        bf16x8 af[4], bfr[4];
#pragma unroll
        for (int f = 0; f < 4; ++f) {
            af[f]  = *(const bf16x8*)((const char*)ldsA[cur] + (wm + f * 16 + fr) * 64 + pslot);
            bfr[f] = *(const bf16x8*)((const char*)ldsB[cur] + (wn + f * 16 + fr) * 64 + pslot);
        }
#pragma unroll
        for (int i = 0; i < 4; ++i)
#pragma unroll
            for (int j = 0; j < 4; ++j)
                acc[i][j] = __builtin_amdgcn_mfma_f32_16x16x32_bf16(af[i], bfr[j], acc[i][j], 0, 0, 0);
        cur = cur + 1; if (cur >= 3) cur = 0;
    }
    float* ob = out + (size_t)b * DQ * NQ;
    const float* fb = feat + (size_t)b * DQ * NQ;
#pragma unroll
    for (int i = 0; i < 4; ++i)
#pragma unroll
        for (int j = 0; j < 4; ++j) {
            int dbase = m0 + wm + i * 16 + fg * 4;
            int n = n0 + wn + j * 16 + fr;
#pragma unroll
            for (int r = 0; r < 4; ++r) {
                int d = dbase + r;
                size_t idx = (size_t)d * NQ + n;
                ob[idx] = acc[i][j][r] + fb[idx] + bout[d];
            }
        }
}

// ---------------------------------------------------------------------------
// MFMA attention per (b, h, 256 q-rows). RoPE via precomputed f32 table
// (tab[p][0:32]=cos, [32:64]=sin). K staged with fused RoPE (bf16), V staged
// transposed (bf16); both held as register fragments per wave. Q frags loaded
// from global, RoPE'd in-register with 1/8 scale folded in. P/out bounce
// through a wave-private LDS tile. Writes ao (bf16) IN PLACE over q.
// ---------------------------------------------------------------------------
__global__ __launch_bounds__(256) void attn_mfma(const float* __restrict__ kv,
                                                 const float* __restrict__ tab,
                                                 unsigned short* __restrict__ q) {
    const int qb = blockIdx.x, h = blockIdx.y, b = blockIdx.z;
    const int n0 = qb * 256;
    __shared__ __align__(16) unsigned short Ks[64][72];   // RoPE'd K, [t][d]
    __shared__ __align__(16) unsigned short VT[64][72];   // V^T, [d][t]
    __shared__ __align__(16) unsigned short Ps[4][16][72];// per-wave P/out bounce
    const int tid = threadIdx.x;
    const int lane = tid & 63;
    const int wid = tid >> 6;
    const int fr = lane & 15;   // frag row/col index
    const int fg = lane >> 4;   // frag k-group

    // ---- stage K with RoPE (table) ----
    {
        const int t = tid >> 2, dg = (tid & 3) * 8;
        const float* krow = kv + ((size_t)b * NT + t) * (2 * DQ) + h * HD;
        const float* trow = tab + t * 64 + dg;
        float lo[8], hi[8], c[8], s[8];
        *(float4*)&lo[0] = *(const float4*)(krow + dg);
        *(float4*)&lo[4] = *(const float4*)(krow + dg + 4);
        *(float4*)&hi[0] = *(const float4*)(krow + dg + 32);
        *(float4*)&hi[4] = *(const float4*)(krow + dg + 36);
        *(float4*)&c[0] = *(const float4*)(trow);
        *(float4*)&c[4] = *(const float4*)(trow + 4);
        *(float4*)&s[0] = *(const float4*)(trow + 32);
        *(float4*)&s[4] = *(const float4*)(trow + 36);
        union { bf16x8 v; unsigned short u[8]; } plo, phi;
#pragma unroll
        for (int e = 0; e < 8; ++e) {
            plo.u[e] = f2bf(lo[e] * c[e] - hi[e] * s[e]);
            phi.u[e] = f2bf(hi[e] * c[e] + lo[e] * s[e]);
        }
        *(bf16x8*)&Ks[t][dg]      = plo.v;
        *(bf16x8*)&Ks[t][dg + 32] = phi.v;
    }
    // ---- stage V transposed ----
    {
        const int t = tid >> 2, d0 = (tid & 3) * 16;
        const float* vrow = kv + ((size_t)b * NT + t) * (2 * DQ) + DQ + h * HD + d0;
        float vv[16];
        *(float4*)&vv[0]  = *(const float4*)(vrow + 0);
        *(float4*)&vv[4]  = *(const float4*)(vrow + 4);
        *(float4*)&vv[8]  = *(const float4*)(vrow + 8);
        *(float4*)&vv[12] = *(const float4*)(vrow + 12);
#pragma unroll
        for (int dd = 0; dd < 16; ++dd)
            VT[d0 + dd][t] = f2bf(vv[dd]);
    }
    __syncthreads();

    // ---- K, V fragments to registers (held for whole kernel) ----
    bf16x8 kf[4][2], vf[4][2];
#pragma unroll
    for (int j = 0; j < 4; ++j)
#pragma unroll
        for (int hh = 0; hh < 2; ++hh) {
            kf[j][hh] = *(const bf16x8*)&Ks[j * 16 + fr][hh * 32 + fg * 8];
            vf[j][hh] = *(const bf16x8*)&VT[j * 16 + fr][hh * 32 + fg * 8];
        }

    unsigned short* qbase = q + ((size_t)b * NQ + n0) * DQ + h * HD;

    for (int rt = wid; rt < 16; rt += 4) {
        const int row = rt * 16 + fr;
        const unsigned short* qrow = qbase + (size_t)row * DQ + fg * 8;
        bf16x8 q0 = *(const bf16x8*)qrow;          // d = fg*8..+8
        bf16x8 q1 = *(const bf16x8*)(qrow + 32);   // d+32
        const float* trow = tab + (size_t)(n0 + row) * 64 + fg * 8;
        float c[8], s[8];
        *(float4*)&c[0] = *(const float4*)(trow);
        *(float4*)&c[4] = *(const float4*)(trow + 4);
        *(float4*)&s[0] = *(const float4*)(trow + 32);
        *(float4*)&s[4] = *(const float4*)(trow + 36);
        union { bf16x8 v; unsigned short u[8]; } qa, qb2;
#pragma unroll
        for (int e = 0; e < 8; ++e) {
            float v0 = bf2f((unsigned short)q0[e]);
            float v1 = bf2f((unsigned short)q1[e]);
            qa.u[e]  = f2bf((v0 * c[e] - v1 * s[e]) * 0.125f);   // fold hd^-0.5
            qb2.u[e] = f2bf((v1 * c[e] + v0 * s[e]) * 0.125f);
        }
        // S = Q K^T : 4 col-tiles x 2 k-halves
        f32x4 sc[4];
#pragma unroll
        for (int j = 0; j < 4; ++j) {
            f32x4 z = {};
            sc[j] = __builtin_amdgcn_mfma_f32_16x16x32_bf16(qa.v, kf[j][0], z, 0, 0, 0);
            sc[j] = __builtin_amdgcn_mfma_f32_16x16x32_bf16(qb2.v, kf[j][1], sc[j], 0, 0, 0);
        }
        // softmax over t: lane holds S[q=(fg*4+r)][t=j*16+fr]; reduce over fr
#pragma unroll
        for (int r = 0; r < 4; ++r) {
            float m = fmaxf(fmaxf(sc[0][r], sc[1][r]), fmaxf(sc[2][r], sc[3][r]));
            for (int off = 1; off < 16; off <<= 1) m = fmaxf(m, __shfl_xor(m, off));
            float s2 = 0.f;
#pragma unroll
            for (int j = 0; j < 4; ++j) { float p = __expf(sc[j][r] - m); sc[j][r] = p; s2 += p; }
            for (int off = 1; off < 16; off <<= 1) s2 += __shfl_xor(s2, off);
            float is = 1.0f / s2;
#pragma unroll
            for (int j = 0; j < 4; ++j) sc[j][r] *= is;
        }
        // P scatter (D-layout) -> LDS -> reload as A-frags
#pragma unroll
        for (int r = 0; r < 4; ++r)
#pragma unroll
            for (int j = 0; j < 4; ++j)
                Ps[wid][fg * 4 + r][j * 16 + fr] = f2bf(sc[j][r]);
        bf16x8 pa0 = *(const bf16x8*)&Ps[wid][fr][fg * 8];
        bf16x8 pa1 = *(const bf16x8*)&Ps[wid][fr][32 + fg * 8];
        // out = P V : 4 d-tiles x 2 t-halves; scatter result into same LDS tile
#pragma unroll
        for (int n = 0; n < 4; ++n) {
            f32x4 z = {};
            f32x4 o = __builtin_amdgcn_mfma_f32_16x16x32_bf16(pa0, vf[n][0], z, 0, 0, 0);
            o = __builtin_amdgcn_mfma_f32_16x16x32_bf16(pa1, vf[n][1], o, 0, 0, 0);
#pragma unroll
            for (int r = 0; r < 4; ++r)
                Ps[wid][fg * 4 + r][n * 16 + fr] = f2bf(o[r]);
        }
        // coalesced writeback (in place over q)
#pragma unroll
        for (int p = 0; p < 2; ++p) {
            int rr = p * 8 + (lane >> 3), ch = lane & 7;
            bf16x8 ov = *(const bf16x8*)&Ps[wid][rr][ch * 8];
            *(bf16x8*)(qbase + (size_t)(rt * 16 + rr) * DQ + ch * 8) = ov;
        }
    }
}

// ---------------------------------------------------------------------------
extern "C" void kernel_launch(void* const* d_in, const int* in_sizes, int n_in,
                              void* d_out, int out_size, void* d_ws, size_t ws_size,
                              hipStream_t stream) {
    const float* feat   = (const float*)d_in[0];
    const float* tokens = (const float*)d_in[1];
    const float* Wq     = (const float*)d_in[2];
    const float* Wkv    = (const float*)d_in[3];
    const float* Wout   = (const float*)d_in[4];
    const float* bout   = (const float*)d_in[5];
    float* out = (float*)d_out;

    float* ws_kv = (float*)d_ws;                                        // [B][NT][2*DQ] f32
    unsigned short* ws_featT = (unsigned short*)(ws_kv + (size_t)BATCH * NT * 2 * DQ);  // [B][NQ][DQ] bf16
    unsigned short* ws_q     = ws_featT + (size_t)BATCH * NQ * DQ;      // [B][NQ][DQ] bf16 (q, then ao in place)
    unsigned short* ws_WqT   = ws_q + (size_t)BATCH * NQ * DQ;          // [DQ][DQ] bf16
    unsigned short* ws_WoutT = ws_WqT + (size_t)DQ * DQ;                // [DQ][DQ] bf16
    float* ws_rope = (float*)ws_featT;   // 256KB RoPE table, reuses featT AFTER gemm_q

    conv_w_k<<<dim3(12, 12, 2), 256, 0, stream>>>(Wq, Wout, ws_WqT, ws_WoutT);
    conv_feat_k<<<dim3(16, 12, BATCH), 256, 0, stream>>>(feat, ws_featT);
    gemm_kv_k<<<dim3(24, 1, BATCH), 256, 0, stream>>>(tokens, Wkv, ws_kv);
    gemm_q_mfma<<<dim3(8, 6, BATCH), 256, 0, stream>>>(ws_featT, ws_WqT, ws_q);
    rope_tab_k<<<dim3(NQ), 32, 0, stream>>>(ws_rope);                   // featT dead now
    attn_mfma<<<dim3(4, 12, BATCH), 256, 0, stream>>>(ws_kv, ws_rope, ws_q);
    gemm_out_mfma<<<dim3(6, 8, BATCH), 256, 0, stream>>>(ws_WoutT, ws_q, feat, bout, out);
}